// Round 1
// baseline (936.289 us; speedup 1.0000x reference)
//
#include <hip/hip_runtime.h>

// Refine: out = relu((1-a)*(W f) + a*(W cent[idx]) + bias)
// a = exp(-(csq - 2*<f,cent[idx]> + fsq)/256)
// idx = argmax_n <f, cnorm_n>   (feature norm is argmax-invariant)
//
// ws layout (needs ~5.9 MB):
//  cnT    [256][80] f32      @ 0
//  idx    [16*16384] i32     @ 81920
//  fsq    [16*16384] f32     @ 1130496
//  sumx   [16][80][256] f32  @ 2179072
//  cnt    [16][80] f32       @ 3489792
//  csq    [16][80] f32       @ 3494912
//  chat   [16][80][256] f32  @ 3500032
//  centks [16][8][80][32] bf16 @ 4810752
//  wks    [8][256][32] bf16  @ 5466112
//  wt     [256][256] f32     @ 5597184   (W^T for K2)

typedef __bf16 bf16x8 __attribute__((ext_vector_type(8)));
typedef float  f32x4  __attribute__((ext_vector_type(4)));

__device__ __forceinline__ unsigned short f2b(float f) {
  unsigned u = __float_as_uint(f);
  return (unsigned short)((u + 0x7fffu + ((u >> 16) & 1u)) >> 16);
}

// ---------------- K0a: normalized centroids, transposed [c][n] ----------------
__global__ __launch_bounds__(256) void k0_cnorm(const float* __restrict__ cent,
                                                float* __restrict__ cnT) {
  int n = blockIdx.x, t = threadIdx.x;
  float v = cent[n * 256 + t];
  float s = v * v;
  #pragma unroll
  for (int o = 32; o > 0; o >>= 1) s += __shfl_down(s, o, 64);
  __shared__ float red[4];
  if ((t & 63) == 0) red[t >> 6] = s;
  __syncthreads();
  float tot = red[0] + red[1] + red[2] + red[3];
  float dn = fmaxf(sqrtf(tot), 1e-12f);
  cnT[t * 80 + n] = v / dn;
}

// ---------------- K0b: W prep: bf16 k-sliced [k][o][32] + W^T f32 -------------
__global__ __launch_bounds__(256) void k0_wprep(const float* __restrict__ fcw,
                                                unsigned short* __restrict__ wks,
                                                float* __restrict__ wt) {
  int o = blockIdx.x, c = threadIdx.x;
  float w = fcw[o * 256 + c];
  wt[c * 256 + o] = w;
  wks[((c >> 5) * 256 + o) * 32 + (c & 31)] = f2b(w);
}

// ---------------- K1: per-pixel argmax over 80 dots (f32) + fsq ---------------
__global__ __launch_bounds__(256) void k1_argmax(const float* __restrict__ feat,
                                                 const float* __restrict__ cnT,
                                                 int* __restrict__ idxg,
                                                 float* __restrict__ fsqg) {
  int b = blockIdx.x >> 6;                       // 64 blocks/image
  int pi = ((blockIdx.x & 63) << 8) | threadIdx.x;
  const float* fb = feat + (size_t)b * 256 * 16384 + pi;
  float g[80];
  #pragma unroll
  for (int n = 0; n < 80; ++n) g[n] = 0.f;
  float fsq = 0.f;
  #pragma unroll 4
  for (int c = 0; c < 256; ++c) {
    float v = fb[(size_t)c * 16384];             // coalesced (pixels in lanes)
    fsq = fmaf(v, v, fsq);
    const float* cr = cnT + c * 80;              // uniform address -> s_load
    #pragma unroll
    for (int n = 0; n < 80; ++n) g[n] = fmaf(v, cr[n], g[n]);
  }
  float best = g[0]; int bi = 0;
  #pragma unroll
  for (int n = 1; n < 80; ++n) if (g[n] > best) { best = g[n]; bi = n; }
  idxg[b * 16384 + pi] = bi;
  fsqg[b * 16384 + pi] = fsq;
}

// ---------------- K1b: segmented class sums + counts (LDS atomics) ------------
__global__ __launch_bounds__(256) void k1b_sums(const float* __restrict__ feat,
                                                const int* __restrict__ idxg,
                                                float* __restrict__ sumx,
                                                float* __restrict__ cntg) {
  int b = blockIdx.x >> 5;                       // 32 c-chunks/image
  int c0 = (blockIdx.x & 31) * 8;
  __shared__ float ls[8][80];
  __shared__ float lc[80];
  int t = threadIdx.x;
  for (int i = t; i < 640; i += 256) (&ls[0][0])[i] = 0.f;
  if (t < 80) lc[t] = 0.f;
  __syncthreads();
  const float* fb = feat + ((size_t)b * 256 + c0) * 16384;
  const int* ib = idxg + b * 16384;
  for (int p = t; p < 16384; p += 256) {
    int n = ib[p];
    #pragma unroll
    for (int j = 0; j < 8; ++j) atomicAdd(&ls[j][n], fb[(size_t)j * 16384 + p]);
    if (c0 == 0) atomicAdd(&lc[n], 1.f);
  }
  __syncthreads();
  for (int i = t; i < 640; i += 256) {
    int j = i / 80, n = i - j * 80;
    sumx[((size_t)b * 80 + n) * 256 + c0 + j] = ls[j][n];  // block-owned, no atomics
  }
  if (c0 == 0 && t < 80) cntg[b * 80 + t] = lc[t];
}

// ---------------- K2: cent = sum/max(cnt,1); csq; chat = W*cent ---------------
__global__ __launch_bounds__(256) void k2_cent(const float* __restrict__ sumx,
                                               const float* __restrict__ cntg,
                                               const float* __restrict__ wt,
                                               unsigned short* __restrict__ centks,
                                               float* __restrict__ csqg,
                                               float* __restrict__ chatg) {
  int bn = blockIdx.x; int b = bn / 80, n = bn - b * 80; int t = threadIdx.x;
  float dn = fmaxf(cntg[bn], 1.0f);
  float cv = sumx[(size_t)bn * 256 + t] / dn;
  __shared__ float cl[256];
  __shared__ float red[4];
  cl[t] = cv;
  centks[(((size_t)b * 8 + (t >> 5)) * 80 + n) * 32 + (t & 31)] = f2b(cv);
  float q = cv * cv;
  #pragma unroll
  for (int o = 32; o > 0; o >>= 1) q += __shfl_down(q, o, 64);
  if ((t & 63) == 0) red[t >> 6] = q;
  __syncthreads();
  if (t == 0) csqg[bn] = red[0] + red[1] + red[2] + red[3];
  float acc = 0.f;                               // t = output channel o
  #pragma unroll 4
  for (int c = 0; c < 256; ++c) acc = fmaf(wt[c * 256 + t], cl[c], acc);
  chatg[(size_t)bn * 256 + t] = acc;
}

// ---------------- K3: fused MFMA GEMM [64px x (80 cent + 256 W)] + epilogue ---
__global__ __launch_bounds__(256) void k3_main(const float* __restrict__ feat,
    const int* __restrict__ idxg, const float* __restrict__ fsqg,
    const float* __restrict__ csqg, const float* __restrict__ chatg,
    const unsigned short* __restrict__ centks, const unsigned short* __restrict__ wks,
    const float* __restrict__ fcb, float* __restrict__ out) {
  // featT: [64 px][256 c] bf16, 16B-slot XOR swizzle (G4); reused for chat rows
  __shared__ alignas(16) unsigned short featT[64 * 256];
  __shared__ alignas(16) unsigned short ball[336 * 40];   // rows padded to 80B
  __shared__ float csql[80];
  __shared__ float biasl[256];
  __shared__ int   idxl[64];
  __shared__ float fsql[64];
  __shared__ float alphal[64];

  const int t = threadIdx.x;
  const int b = blockIdx.x >> 8;
  const int p0 = (blockIdx.x & 255) << 6;
  const int wv = t >> 6, ln = t & 63;
  const int lo = ln & 15, hi = ln >> 4;

  if (t < 64) {
    idxl[t] = idxg[b * 16384 + p0 + t];
    fsql[t] = fsqg[b * 16384 + p0 + t];
  }
  if (t < 80) csql[t] = csqg[b * 80 + t];
  biasl[t] = fcb[t];

  { // stage featT: transpose f32[c][p] -> bf16 [p][c], b128 writes (conflict-free)
    const int pl = t & 63, cph = t >> 6;
    const float* fb = feat + ((size_t)b * 256 + cph * 64) * 16384 + p0 + pl;
    #pragma unroll
    for (int jj = 0; jj < 8; ++jj) {
      union { unsigned short u[8]; uint4 q; } pk;
      #pragma unroll
      for (int e = 0; e < 8; ++e) pk.u[e] = f2b(fb[(size_t)(jj * 8 + e) * 16384]);
      int c0 = cph * 64 + jj * 8;
      *(uint4*)&featT[pl * 256 + (c0 ^ ((pl & 7) << 3))] = pk.q;
    }
  }

  f32x4 acc[6][4];
  f32x4 zz = {0.f, 0.f, 0.f, 0.f};
  #pragma unroll
  for (int i = 0; i < 6; ++i)
    #pragma unroll
    for (int j = 0; j < 4; ++j) acc[i][j] = zz;

  const int mbeg = wv * 5;   // waves own m-tiles [5w, 5w+5] (overlap rows benign-dup)
  for (int ks = 0; ks < 8; ++ks) {
    __syncthreads();
    { // stage B_all k-slice: rows 0-79 cent[b], 80-335 W ; linear b128 copies
      const unsigned short* centp = centks + ((size_t)b * 8 + ks) * 80 * 32;
      const unsigned short* wp = wks + (size_t)ks * 256 * 32;
      #pragma unroll
      for (int s = 0; s < 6; ++s) {
        int q = t + s * 256;
        if (q < 1344) {
          int row = q >> 2, slot = q & 3;
          const unsigned short* src = (row < 80) ? (centp + row * 32 + slot * 8)
                                                 : (wp + (row - 80) * 32 + slot * 8);
          *(uint4*)&ball[row * 40 + slot * 8] = *(const uint4*)src;
        }
      }
    }
    __syncthreads();
    bf16x8 bfr[4];
    #pragma unroll
    for (int pt = 0; pt < 4; ++pt) {
      int p = pt * 16 + lo;
      bfr[pt] = *(const bf16x8*)&featT[p * 256 + ((ks * 32 + hi * 8) ^ ((p & 7) << 3))];
    }
    #pragma unroll
    for (int ml = 0; ml < 6; ++ml) {
      int row = (mbeg + ml) * 16 + lo;
      bf16x8 af = *(const bf16x8*)&ball[row * 40 + hi * 8];
      #pragma unroll
      for (int pt = 0; pt < 4; ++pt)
        acc[ml][pt] = __builtin_amdgcn_mfma_f32_16x16x32_bf16(af, bfr[pt], acc[ml][pt], 0, 0, 0);
    }
  }
  __syncthreads();

  // alpha: wave0 holds D rows 0..79 (m-tiles 0..4)
  if (wv == 0) {
    #pragma unroll
    for (int pt = 0; pt < 4; ++pt) {
      int p = pt * 16 + lo;
      int tgt = idxl[p];
      float sel = 0.f;
      #pragma unroll
      for (int ml = 0; ml < 5; ++ml)
        #pragma unroll
        for (int r = 0; r < 4; ++r)
          sel += ((ml * 16 + hi * 4 + r) == tgt) ? acc[ml][pt][r] : 0.f;
      sel += __shfl_xor(sel, 16, 64);
      sel += __shfl_xor(sel, 32, 64);
      float msq = (csql[tgt] - 2.f * sel + fsql[p]) * (1.f / 256.f);
      float a = expf(-msq);
      if (hi == 0) alphal[p] = a;
    }
  }

  { // gather chat rows (per-pixel) into featT (bf16), coalesced 16B loads
    int p = t >> 2, quad = t & 3;
    const float* src = chatg + ((size_t)b * 80 + idxl[p]) * 256;
    #pragma unroll
    for (int j = 0; j < 16; ++j) {
      int o0 = quad * 64 + j * 4;
      float4 v = *(const float4*)&src[o0];
      ushort4 pk;
      pk.x = f2b(v.x); pk.y = f2b(v.y); pk.z = f2b(v.z); pk.w = f2b(v.w);
      *(ushort4*)&featT[p * 256 + (o0 ^ ((p & 7) << 3))] = pk;
    }
  }
  __syncthreads();

  // epilogue: out = relu((1-a)*Fhat + a*chat[idx] + bias)
  #pragma unroll
  for (int ml = 0; ml < 6; ++ml) {
    int m = mbeg + ml;
    if (m < 5) continue;                // skip cent (D) rows
    int ot = m - 5;
    int obase = ot * 16 + hi * 4;
    f32x4 b4 = *(const f32x4*)&biasl[obase];
    #pragma unroll
    for (int pt = 0; pt < 4; ++pt) {
      int p = pt * 16 + lo;
      float a = alphal[p];
      float om = 1.f - a;
      ushort4 cb = *(const ushort4*)&featT[p * 256 + (obase ^ ((p & 7) << 3))];
      float c0 = __uint_as_float((unsigned)cb.x << 16);
      float c1 = __uint_as_float((unsigned)cb.y << 16);
      float c2 = __uint_as_float((unsigned)cb.z << 16);
      float c3 = __uint_as_float((unsigned)cb.w << 16);
      size_t ob = ((size_t)b * 256 + obase) * 16384 + p0 + p;
      out[ob            ] = fmaxf(fmaf(a, c0, om * acc[ml][pt][0]) + b4[0], 0.f);
      out[ob + 16384    ] = fmaxf(fmaf(a, c1, om * acc[ml][pt][1]) + b4[1], 0.f);
      out[ob + 2 * 16384] = fmaxf(fmaf(a, c2, om * acc[ml][pt][2]) + b4[2], 0.f);
      out[ob + 3 * 16384] = fmaxf(fmaf(a, c3, om * acc[ml][pt][3]) + b4[3], 0.f);
    }
  }
}

extern "C" void kernel_launch(void* const* d_in, const int* in_sizes, int n_in,
                              void* d_out, int out_size, void* d_ws, size_t ws_size,
                              hipStream_t stream) {
  (void)in_sizes; (void)n_in; (void)out_size; (void)ws_size;
  const float* feat = (const float*)d_in[0];
  const float* cent = (const float*)d_in[1];
  const float* fcw  = (const float*)d_in[2];
  const float* fcb  = (const float*)d_in[3];
  float* out = (float*)d_out;
  char* ws = (char*)d_ws;
  float* cnT            = (float*)(ws);
  int*   idxq           = (int*)(ws + 81920);
  float* fsq            = (float*)(ws + 1130496);
  float* sumx           = (float*)(ws + 2179072);
  float* cntg           = (float*)(ws + 3489792);
  float* csq            = (float*)(ws + 3494912);
  float* chat           = (float*)(ws + 3500032);
  unsigned short* centks = (unsigned short*)(ws + 4810752);
  unsigned short* wks    = (unsigned short*)(ws + 5466112);
  float* wt             = (float*)(ws + 5597184);

  k0_cnorm<<<80, 256, 0, stream>>>(cent, cnT);
  k0_wprep<<<256, 256, 0, stream>>>(fcw, wks, wt);
  k1_argmax<<<1024, 256, 0, stream>>>(feat, cnT, idxq, fsq);
  k1b_sums<<<512, 256, 0, stream>>>(feat, idxq, sumx, cntg);
  k2_cent<<<1280, 256, 0, stream>>>(sumx, cntg, wt, centks, csq, chat);
  k3_main<<<4096, 256, 0, stream>>>(feat, idxq, fsq, csq, chat, centks, wks, fcb, out);
}

// Round 2
// 697.938 us; speedup vs baseline: 1.3415x; 1.3415x over previous
//
#include <hip/hip_runtime.h>

// Refine: out = relu((1-a)*(W f) + a*(W cent[idx]) + bias)
// a = exp(-(csq - 2*<f,cent[idx]> + fsq)/256)
// idx = argmax_n <f, cnorm_n>   (feature norm is argmax-invariant)
//
// ws layout (~6.4 MB):
//  cnT    [256][80] f32        @ 0
//  wt     [256][256] f32       @ 102400
//  wks    [8][256][32] bf16    @ 364544
//  centks [16][8][80][32] bf16 @ 495616
//  idxb   [16*16384] u8        @ 1150976
//  fsq    [16*16384] f32       @ 1413120
//  cnt    [16*80] i32          @ 2461696   (memset 0 each launch; int atomics)
//  csq    [16*80] f32          @ 2466816
//  chat   [16][80][256] f32    @ 2471936
//  sumxp  [4][16][80][256] bf16 @ 3782656  (split-K partials, deterministic)

typedef __bf16 bf16x8 __attribute__((ext_vector_type(8)));
typedef float  f32x4  __attribute__((ext_vector_type(4)));
typedef unsigned char u8;

__device__ __forceinline__ unsigned short f2b(float f) {
  unsigned u = __float_as_uint(f);
  return (unsigned short)((u + 0x7fffu + ((u >> 16) & 1u)) >> 16);
}
__device__ __forceinline__ float b2f(unsigned short s) {
  return __uint_as_float((unsigned)s << 16);
}

// ---------------- K0a: normalized centroids, transposed [c][n] ----------------
__global__ __launch_bounds__(256) void k0_cnorm(const float* __restrict__ cent,
                                                float* __restrict__ cnT) {
  int n = blockIdx.x, t = threadIdx.x;
  float v = cent[n * 256 + t];
  float s = v * v;
  #pragma unroll
  for (int o = 32; o > 0; o >>= 1) s += __shfl_down(s, o, 64);
  __shared__ float red[4];
  if ((t & 63) == 0) red[t >> 6] = s;
  __syncthreads();
  float tot = red[0] + red[1] + red[2] + red[3];
  float dn = fmaxf(sqrtf(tot), 1e-12f);
  cnT[t * 80 + n] = v / dn;
}

// ---------------- K0b: W prep: bf16 k-sliced [k][o][32] + W^T f32 -------------
__global__ __launch_bounds__(256) void k0_wprep(const float* __restrict__ fcw,
                                                unsigned short* __restrict__ wks,
                                                float* __restrict__ wt) {
  int o = blockIdx.x, c = threadIdx.x;
  float w = fcw[o * 256 + c];
  wt[c * 256 + o] = w;
  wks[((c >> 5) * 256 + o) * 32 + (c & 31)] = f2b(w);
}

// ---------------- K1: per-pixel argmax over 80 dots (f32) + fsq + counts ------
__global__ __launch_bounds__(256) void k1_argmax(const float* __restrict__ feat,
                                                 const float* __restrict__ cnT,
                                                 u8* __restrict__ idxb,
                                                 float* __restrict__ fsqg,
                                                 int* __restrict__ cntg) {
  __shared__ int lh[80];
  int t = threadIdx.x;
  if (t < 80) lh[t] = 0;
  __syncthreads();
  int b = blockIdx.x >> 6;                       // 64 blocks/image
  int pi = ((blockIdx.x & 63) << 8) | t;
  const float* fb = feat + (size_t)b * 256 * 16384 + pi;
  float g[80];
  #pragma unroll
  for (int n = 0; n < 80; ++n) g[n] = 0.f;
  float fsq = 0.f;
  #pragma unroll 4
  for (int c = 0; c < 256; ++c) {
    float v = fb[(size_t)c * 16384];             // coalesced (pixels in lanes)
    fsq = fmaf(v, v, fsq);
    const float* cr = cnT + c * 80;              // uniform address
    #pragma unroll
    for (int n = 0; n < 80; ++n) g[n] = fmaf(v, cr[n], g[n]);
  }
  float best = g[0]; int bi = 0;
  #pragma unroll
  for (int n = 1; n < 80; ++n) if (g[n] > best) { best = g[n]; bi = n; }
  idxb[b * 16384 + pi] = (u8)bi;
  fsqg[b * 16384 + pi] = fsq;
  atomicAdd(&lh[bi], 1);
  __syncthreads();
  if (t < 80) atomicAdd(&cntg[b * 80 + t], lh[t]);
}

// ---------------- K1b: sumx = onehot(idx) * feat^T via MFMA (split-K=4) -------
__global__ __launch_bounds__(256) void k1b_gemm(const float* __restrict__ feat,
                                                const u8* __restrict__ idxb,
                                                unsigned short* __restrict__ sumxp) {
  // grid: b(16) x nslice(8, 32ch) x ksplit(4, 4096px)
  int bid = blockIdx.x;
  int kp = bid & 3, ns = (bid >> 2) & 7, b = bid >> 5;
  int t = threadIdx.x, wv = t >> 6, ln = t & 63, lo = ln & 15, hi = ln >> 4;
  int nt = wv & 1;                   // n-tile (16ch) within slice
  int m0 = (wv >> 1) ? 3 : 0, nm = (wv >> 1) ? 2 : 3;  // class m-tiles owned
  int c = ns * 32 + nt * 16 + lo;
  const float* fp = feat + (((size_t)b * 256 + c) * 16384 + kp * 4096 + hi * 8);
  const u8* ip = idxb + b * 16384 + kp * 4096 + hi * 8;
  f32x4 acc[3];
  f32x4 zz = {0.f, 0.f, 0.f, 0.f};
  acc[0] = zz; acc[1] = zz; acc[2] = zz;
  for (int ks = 0; ks < 128; ++ks) {
    float4 v0 = *(const float4*)(fp + ks * 32);
    float4 v1 = *(const float4*)(fp + ks * 32 + 4);
    union { unsigned short u[8]; bf16x8 v; } bb;
    bb.u[0] = f2b(v0.x); bb.u[1] = f2b(v0.y); bb.u[2] = f2b(v0.z); bb.u[3] = f2b(v0.w);
    bb.u[4] = f2b(v1.x); bb.u[5] = f2b(v1.y); bb.u[6] = f2b(v1.z); bb.u[7] = f2b(v1.w);
    uint2 iv = *(const uint2*)(ip + ks * 32);
    int id[8];
    #pragma unroll
    for (int j = 0; j < 4; ++j) { id[j] = (iv.x >> (8 * j)) & 255; id[4 + j] = (iv.y >> (8 * j)) & 255; }
    #pragma unroll
    for (int mi = 0; mi < 3; ++mi) {
      if (mi >= nm) break;
      int row = (m0 + mi) * 16 + lo;
      union { unsigned short u[8]; bf16x8 v; } ma;
      #pragma unroll
      for (int j = 0; j < 8; ++j) ma.u[j] = (id[j] == row) ? (unsigned short)0x3F80 : (unsigned short)0;
      acc[mi] = __builtin_amdgcn_mfma_f32_16x16x32_bf16(ma.v, bb.v, acc[mi], 0, 0, 0);
    }
  }
  #pragma unroll
  for (int mi = 0; mi < 3; ++mi) {
    if (mi >= nm) break;
    #pragma unroll
    for (int r = 0; r < 4; ++r) {
      int cls = (m0 + mi) * 16 + hi * 4 + r;
      sumxp[(((size_t)kp * 16 + b) * 80 + cls) * 256 + ns * 32 + nt * 16 + lo] = f2b(acc[mi][r]);
    }
  }
}

// ---------------- K2: cent = sum/max(cnt,1); csq; chat = W*cent ---------------
__global__ __launch_bounds__(256) void k2_cent(const unsigned short* __restrict__ sumxp,
                                               const int* __restrict__ cntg,
                                               const float* __restrict__ wt,
                                               unsigned short* __restrict__ centks,
                                               float* __restrict__ csqg,
                                               float* __restrict__ chatg) {
  int bn = blockIdx.x; int b = bn / 80, n = bn - b * 80; int t = threadIdx.x;
  float dn = fmaxf((float)cntg[bn], 1.0f);
  float s = 0.f;
  #pragma unroll
  for (int kp = 0; kp < 4; ++kp)
    s += b2f(sumxp[(((size_t)kp * 16 + b) * 80 + n) * 256 + t]);
  float cv = s / dn;
  __shared__ float cl[256];
  __shared__ float red[4];
  cl[t] = cv;
  centks[(((size_t)b * 8 + (t >> 5)) * 80 + n) * 32 + (t & 31)] = f2b(cv);
  float q = cv * cv;
  #pragma unroll
  for (int o = 32; o > 0; o >>= 1) q += __shfl_down(q, o, 64);
  if ((t & 63) == 0) red[t >> 6] = q;
  __syncthreads();
  if (t == 0) csqg[bn] = red[0] + red[1] + red[2] + red[3];
  float acc = 0.f;                               // t = output channel o
  #pragma unroll 4
  for (int c = 0; c < 256; ++c) acc = fmaf(wt[c * 256 + t], cl[c], acc);
  chatg[(size_t)bn * 256 + t] = acc;
}

// ---------------- K3: fused MFMA GEMM, A-fragments direct from global ---------
__global__ __launch_bounds__(256) void k3_main(const float* __restrict__ feat,
    const u8* __restrict__ idxb, const float* __restrict__ fsqg,
    const float* __restrict__ csqg, const float* __restrict__ chatg,
    const unsigned short* __restrict__ centks, const unsigned short* __restrict__ wks,
    const float* __restrict__ fcb, float* __restrict__ out) {
  // featT: [64 px][256 c] bf16, 16B-slot XOR swizzle; reused for chat rows
  __shared__ alignas(16) unsigned short featT[64 * 256];
  __shared__ float csql[80];
  __shared__ float biasl[256];
  __shared__ int   idxl[64];
  __shared__ float fsql[64];
  __shared__ float alphal[64];

  const int t = threadIdx.x;
  const int b = blockIdx.x >> 8;
  const int p0 = (blockIdx.x & 255) << 6;
  const int wv = t >> 6, ln = t & 63;
  const int lo = ln & 15, hi = ln >> 4;

  if (t < 64) {
    idxl[t] = (int)idxb[b * 16384 + p0 + t];
    fsql[t] = fsqg[b * 16384 + p0 + t];
  }
  if (t < 80) csql[t] = csqg[b * 80 + t];
  biasl[t] = fcb[t];

  { // stage featT: transpose f32[c][p] -> bf16 [p][c], b128 swizzled writes
    const int pl = t & 63, cph = t >> 6;
    const float* fb = feat + ((size_t)b * 256 + cph * 64) * 16384 + p0 + pl;
    #pragma unroll
    for (int jj = 0; jj < 8; ++jj) {
      union { unsigned short u[8]; uint4 q; } pk;
      #pragma unroll
      for (int e = 0; e < 8; ++e) pk.u[e] = f2b(fb[(size_t)(jj * 8 + e) * 16384]);
      int c0 = cph * 64 + jj * 8;
      *(uint4*)&featT[pl * 256 + (c0 ^ ((pl & 7) << 3))] = pk.q;
    }
  }
  __syncthreads();

  f32x4 acc[6][4];
  f32x4 zz = {0.f, 0.f, 0.f, 0.f};
  #pragma unroll
  for (int i = 0; i < 6; ++i)
    #pragma unroll
    for (int j = 0; j < 4; ++j) acc[i][j] = zz;

  const int mbeg = wv * 5;   // waves own m-tiles [5w, 5w+5]; dup tiles benign
  const unsigned short* centb = centks + (size_t)b * 8 * 80 * 32;
  // k-loop: NO barriers — featT read-only, A-fragments from L2-hot global
  for (int ks = 0; ks < 8; ++ks) {
    bf16x8 bfr[4];
    #pragma unroll
    for (int pt = 0; pt < 4; ++pt) {
      int p = pt * 16 + lo;
      bfr[pt] = *(const bf16x8*)&featT[p * 256 + ((ks * 32 + hi * 8) ^ ((p & 7) << 3))];
    }
    #pragma unroll
    for (int ml = 0; ml < 6; ++ml) {
      int mt = mbeg + ml;
      const unsigned short* src = (mt < 5)
          ? centb + ((size_t)ks * 80 + mt * 16 + lo) * 32 + hi * 8
          : wks + ((size_t)ks * 256 + (mt - 5) * 16 + lo) * 32 + hi * 8;
      bf16x8 af = *(const bf16x8*)src;           // 16B/lane, 1KB/wave, L2-hot
      #pragma unroll
      for (int pt = 0; pt < 4; ++pt)
        acc[ml][pt] = __builtin_amdgcn_mfma_f32_16x16x32_bf16(af, bfr[pt], acc[ml][pt], 0, 0, 0);
    }
  }
  __syncthreads();   // all waves done reading featT before overwrite

  // alpha: wave0 holds cent rows 0..79 (m-tiles 0..4)
  if (wv == 0) {
    #pragma unroll
    for (int pt = 0; pt < 4; ++pt) {
      int p = pt * 16 + lo;
      int tgt = idxl[p];
      float sel = 0.f;
      #pragma unroll
      for (int ml = 0; ml < 5; ++ml)
        #pragma unroll
        for (int r = 0; r < 4; ++r)
          sel += ((ml * 16 + hi * 4 + r) == tgt) ? acc[ml][pt][r] : 0.f;
      sel += __shfl_xor(sel, 16, 64);
      sel += __shfl_xor(sel, 32, 64);
      float msq = (csql[tgt] - 2.f * sel + fsql[p]) * (1.f / 256.f);
      float a = expf(-msq);
      if (hi == 0) alphal[p] = a;
    }
  }

  { // gather chat rows (per-pixel) into featT (bf16)
    int p = t >> 2, quad = t & 3;
    const float* src = chatg + ((size_t)b * 80 + idxl[p]) * 256;
    #pragma unroll
    for (int j = 0; j < 16; ++j) {
      int o0 = quad * 64 + j * 4;
      float4 v = *(const float4*)&src[o0];
      ushort4 pk;
      pk.x = f2b(v.x); pk.y = f2b(v.y); pk.z = f2b(v.z); pk.w = f2b(v.w);
      *(ushort4*)&featT[p * 256 + (o0 ^ ((p & 7) << 3))] = pk;
    }
  }
  __syncthreads();

  // epilogue: out = relu((1-a)*Fhat + a*chat[idx] + bias)
  #pragma unroll
  for (int ml = 0; ml < 6; ++ml) {
    int m = mbeg + ml;
    if (m < 5) continue;                // skip cent (alpha) rows
    int obase = (m - 5) * 16 + hi * 4;
    f32x4 b4 = *(const f32x4*)&biasl[obase];
    #pragma unroll
    for (int pt = 0; pt < 4; ++pt) {
      int p = pt * 16 + lo;
      float a = alphal[p];
      float om = 1.f - a;
      ushort4 cb = *(const ushort4*)&featT[p * 256 + (obase ^ ((p & 7) << 3))];
      float c0 = b2f(cb.x), c1 = b2f(cb.y), c2 = b2f(cb.z), c3 = b2f(cb.w);
      size_t ob = ((size_t)b * 256 + obase) * 16384 + p0 + p;
      out[ob            ] = fmaxf(fmaf(a, c0, om * acc[ml][pt][0]) + b4[0], 0.f);
      out[ob + 16384    ] = fmaxf(fmaf(a, c1, om * acc[ml][pt][1]) + b4[1], 0.f);
      out[ob + 2 * 16384] = fmaxf(fmaf(a, c2, om * acc[ml][pt][2]) + b4[2], 0.f);
      out[ob + 3 * 16384] = fmaxf(fmaf(a, c3, om * acc[ml][pt][3]) + b4[3], 0.f);
    }
  }
}

extern "C" void kernel_launch(void* const* d_in, const int* in_sizes, int n_in,
                              void* d_out, int out_size, void* d_ws, size_t ws_size,
                              hipStream_t stream) {
  (void)in_sizes; (void)n_in; (void)out_size; (void)ws_size;
  const float* feat = (const float*)d_in[0];
  const float* cent = (const float*)d_in[1];
  const float* fcw  = (const float*)d_in[2];
  const float* fcb  = (const float*)d_in[3];
  float* out = (float*)d_out;
  char* ws = (char*)d_ws;
  float* cnT             = (float*)(ws);
  float* wt              = (float*)(ws + 102400);
  unsigned short* wks    = (unsigned short*)(ws + 364544);
  unsigned short* centks = (unsigned short*)(ws + 495616);
  u8*    idxb            = (u8*)(ws + 1150976);
  float* fsq             = (float*)(ws + 1413120);
  int*   cntg            = (int*)(ws + 2461696);
  float* csq             = (float*)(ws + 2466816);
  float* chat            = (float*)(ws + 2471936);
  unsigned short* sumxp  = (unsigned short*)(ws + 3782656);

  hipMemsetAsync(cntg, 0, 16 * 80 * sizeof(int), stream);
  k0_cnorm<<<80, 256, 0, stream>>>(cent, cnT);
  k0_wprep<<<256, 256, 0, stream>>>(fcw, wks, wt);
  k1_argmax<<<1024, 256, 0, stream>>>(feat, cnT, idxb, fsq, cntg);
  k1b_gemm<<<512, 256, 0, stream>>>(feat, idxb, sumxp);
  k2_cent<<<1280, 256, 0, stream>>>(sumxp, cntg, wt, centks, csq, chat);
  k3_main<<<4096, 256, 0, stream>>>(feat, idxb, fsq, csq, chat, centks, wks, fcb, out);
}

// Round 4
// 482.518 us; speedup vs baseline: 1.9404x; 1.4464x over previous
//
#include <hip/hip_runtime.h>

// Refine: out = relu((1-a)*(W f) + a*chat[idx] + bias)
// a = exp(-(csq - 2*<f,cent[idx]> + fsq)/256), chat = W*cent
// idx = argmax_n <f, cnorm_n>
//
// ws layout (6.38 MB):
//  cnT    [256][80] f32        @ 0
//  wt     [256][256] f32       @ 81920
//  wks    [8][256][32] bf16    @ 344064
//  centf  [16][80][256] bf16   @ 475136
//  idxb   [16*16384] u8        @ 1130496
//  fsq/alpha [16*16384] f32    @ 1392640  (K1 writes fsq, K3a overwrites with alpha)
//  cnt    [16*80] i32          @ 2441216  (memset 0 each launch)
//  csq    [16*80] f32          @ 2446336
//  chat   [16][80][256] f32    @ 2451456
//  sumxp  [4][16][80][256] bf16 @ 3762176

typedef __bf16 bf16x8 __attribute__((ext_vector_type(8)));
typedef float  f32x4  __attribute__((ext_vector_type(4)));
typedef unsigned char u8;

__device__ __forceinline__ unsigned short f2b(float f) {
  unsigned u = __float_as_uint(f);
  return (unsigned short)((u + 0x7fffu + ((u >> 16) & 1u)) >> 16);
}
__device__ __forceinline__ float b2f(unsigned short s) {
  return __uint_as_float((unsigned)s << 16);
}

// ---------------- K0a: normalized centroids, transposed [c][n] ----------------
__global__ __launch_bounds__(256) void k0_cnorm(const float* __restrict__ cent,
                                                float* __restrict__ cnT) {
  int n = blockIdx.x, t = threadIdx.x;
  float v = cent[n * 256 + t];
  float s = v * v;
  #pragma unroll
  for (int o = 32; o > 0; o >>= 1) s += __shfl_down(s, o, 64);
  __shared__ float red[4];
  if ((t & 63) == 0) red[t >> 6] = s;
  __syncthreads();
  float tot = red[0] + red[1] + red[2] + red[3];
  float dn = fmaxf(sqrtf(tot), 1e-12f);
  cnT[t * 80 + n] = v / dn;
}

// ---------------- K0b: W prep: bf16 k-sliced [k][o][32] + W^T f32 -------------
__global__ __launch_bounds__(256) void k0_wprep(const float* __restrict__ fcw,
                                                unsigned short* __restrict__ wks,
                                                float* __restrict__ wt) {
  int o = blockIdx.x, c = threadIdx.x;
  float w = fcw[o * 256 + c];
  wt[c * 256 + o] = w;
  wks[((c >> 5) * 256 + o) * 32 + (c & 31)] = f2b(w);
}

// ---------------- K1: per-pixel argmax over 80 dots (f32) + fsq + counts ------
__global__ __launch_bounds__(256) void k1_argmax(const float* __restrict__ feat,
                                                 const float* __restrict__ cnT,
                                                 u8* __restrict__ idxb,
                                                 float* __restrict__ fsqg,
                                                 int* __restrict__ cntg) {
  __shared__ int lh[80];
  int t = threadIdx.x;
  if (t < 80) lh[t] = 0;
  __syncthreads();
  int b = blockIdx.x >> 6;
  int pi = ((blockIdx.x & 63) << 8) | t;
  const float* fb = feat + (size_t)b * 256 * 16384 + pi;
  float g[80];
  #pragma unroll
  for (int n = 0; n < 80; ++n) g[n] = 0.f;
  float fsq = 0.f;
  #pragma unroll 4
  for (int c = 0; c < 256; ++c) {
    float v = fb[(size_t)c * 16384];
    fsq = fmaf(v, v, fsq);
    const float* cr = cnT + c * 80;
    #pragma unroll
    for (int n = 0; n < 80; ++n) g[n] = fmaf(v, cr[n], g[n]);
  }
  float best = g[0]; int bi = 0;
  #pragma unroll
  for (int n = 1; n < 80; ++n) if (g[n] > best) { best = g[n]; bi = n; }
  idxb[b * 16384 + pi] = (u8)bi;
  fsqg[b * 16384 + pi] = fsq;
  atomicAdd(&lh[bi], 1);
  __syncthreads();
  if (t < 80) atomicAdd(&cntg[b * 80 + t], lh[t]);
}

// ---------------- K1b: sumx = onehot(idx) * feat^T via MFMA (split-K=4) -------
__global__ __launch_bounds__(256) void k1b_gemm(const float* __restrict__ feat,
                                                const u8* __restrict__ idxb,
                                                unsigned short* __restrict__ sumxp) {
  int bid = blockIdx.x;
  int kp = bid & 3, ns = (bid >> 2) & 7, b = bid >> 5;
  int t = threadIdx.x, wv = t >> 6, ln = t & 63, lo = ln & 15, hi = ln >> 4;
  int nt = wv & 1;
  int m0 = (wv >> 1) ? 3 : 0, nm = (wv >> 1) ? 2 : 3;
  int c = ns * 32 + nt * 16 + lo;
  const float* fp = feat + (((size_t)b * 256 + c) * 16384 + kp * 4096 + hi * 8);
  const u8* ip = idxb + b * 16384 + kp * 4096 + hi * 8;
  f32x4 acc[3];
  f32x4 zz = {0.f, 0.f, 0.f, 0.f};
  acc[0] = zz; acc[1] = zz; acc[2] = zz;
  for (int ks = 0; ks < 128; ++ks) {
    float4 v0 = *(const float4*)(fp + ks * 32);
    float4 v1 = *(const float4*)(fp + ks * 32 + 4);
    union { unsigned short u[8]; bf16x8 v; } bb;
    bb.u[0] = f2b(v0.x); bb.u[1] = f2b(v0.y); bb.u[2] = f2b(v0.z); bb.u[3] = f2b(v0.w);
    bb.u[4] = f2b(v1.x); bb.u[5] = f2b(v1.y); bb.u[6] = f2b(v1.z); bb.u[7] = f2b(v1.w);
    uint2 iv = *(const uint2*)(ip + ks * 32);
    int id[8];
    #pragma unroll
    for (int j = 0; j < 4; ++j) { id[j] = (iv.x >> (8 * j)) & 255; id[4 + j] = (iv.y >> (8 * j)) & 255; }
    #pragma unroll
    for (int mi = 0; mi < 3; ++mi) {
      if (mi >= nm) break;
      int row = (m0 + mi) * 16 + lo;
      union { unsigned short u[8]; bf16x8 v; } ma;
      #pragma unroll
      for (int j = 0; j < 8; ++j) ma.u[j] = (id[j] == row) ? (unsigned short)0x3F80 : (unsigned short)0;
      acc[mi] = __builtin_amdgcn_mfma_f32_16x16x32_bf16(ma.v, bb.v, acc[mi], 0, 0, 0);
    }
  }
  #pragma unroll
  for (int mi = 0; mi < 3; ++mi) {
    if (mi >= nm) break;
    #pragma unroll
    for (int r = 0; r < 4; ++r) {
      int cls = (m0 + mi) * 16 + hi * 4 + r;
      sumxp[(((size_t)kp * 16 + b) * 80 + cls) * 256 + ns * 32 + nt * 16 + lo] = f2b(acc[mi][r]);
    }
  }
}

// ---------------- K2: cent = sum/max(cnt,1); csq; centf bf16; chat = W*cent ---
__global__ __launch_bounds__(256) void k2_cent(const unsigned short* __restrict__ sumxp,
                                               const int* __restrict__ cntg,
                                               const float* __restrict__ wt,
                                               unsigned short* __restrict__ centf,
                                               float* __restrict__ csqg,
                                               float* __restrict__ chatg) {
  int bn = blockIdx.x; int t = threadIdx.x;
  float dn = fmaxf((float)cntg[bn], 1.0f);
  float s = 0.f;
  #pragma unroll
  for (int kp = 0; kp < 4; ++kp)
    s += b2f(sumxp[((size_t)kp * 1280 + bn) * 256 + t]);   // [kp][b][n][c]: (kp*16+b)*80+n = kp*1280+bn
  float cv = s / dn;
  __shared__ float cl[256];
  __shared__ float red[4];
  cl[t] = cv;
  centf[(size_t)bn * 256 + t] = f2b(cv);
  float q = cv * cv;
  #pragma unroll
  for (int o = 32; o > 0; o >>= 1) q += __shfl_down(q, o, 64);
  if ((t & 63) == 0) red[t >> 6] = q;
  __syncthreads();
  if (t == 0) csqg[bn] = red[0] + red[1] + red[2] + red[3];
  float acc = 0.f;
  #pragma unroll 4
  for (int c = 0; c < 256; ++c) acc = fmaf(wt[c * 256 + t], cl[c], acc);
  chatg[(size_t)bn * 256 + t] = acc;
}

// ---------------- K3a: alpha per pixel (streams feat, gathers centf) ----------
__global__ __launch_bounds__(256) void k3a_alpha(const float* __restrict__ feat,
                                                 const u8* __restrict__ idxb,
                                                 const float* __restrict__ csqg,
                                                 const unsigned short* __restrict__ centf,
                                                 float* __restrict__ fsq_alpha) {
  int b = blockIdx.x >> 6;
  int pi = ((blockIdx.x & 63) << 8) | threadIdx.x;
  const float* fb = feat + (size_t)b * 256 * 16384 + pi;
  int idx = idxb[b * 16384 + pi];
  const unsigned short* cw = centf + ((size_t)b * 80 + idx) * 256;
  float sel = 0.f;
  #pragma unroll 4
  for (int c = 0; c < 256; c += 8) {
    uint4 cc = *(const uint4*)&cw[c];              // 8 bf16 (L2-hot gather)
    float v0 = fb[(size_t)(c + 0) * 16384];
    float v1 = fb[(size_t)(c + 1) * 16384];
    float v2 = fb[(size_t)(c + 2) * 16384];
    float v3 = fb[(size_t)(c + 3) * 16384];
    float v4 = fb[(size_t)(c + 4) * 16384];
    float v5 = fb[(size_t)(c + 5) * 16384];
    float v6 = fb[(size_t)(c + 6) * 16384];
    float v7 = fb[(size_t)(c + 7) * 16384];
    sel = fmaf(v0, b2f((unsigned short)(cc.x & 0xffff)), sel);
    sel = fmaf(v1, b2f((unsigned short)(cc.x >> 16)), sel);
    sel = fmaf(v2, b2f((unsigned short)(cc.y & 0xffff)), sel);
    sel = fmaf(v3, b2f((unsigned short)(cc.y >> 16)), sel);
    sel = fmaf(v4, b2f((unsigned short)(cc.z & 0xffff)), sel);
    sel = fmaf(v5, b2f((unsigned short)(cc.z >> 16)), sel);
    sel = fmaf(v6, b2f((unsigned short)(cc.w & 0xffff)), sel);
    sel = fmaf(v7, b2f((unsigned short)(cc.w >> 16)), sel);
  }
  float fsq = fsq_alpha[b * 16384 + pi];
  float msq = (csqg[b * 80 + idx] - 2.f * sel + fsq) * (1.f / 256.f);
  fsq_alpha[b * 16384 + pi] = expf(-msq);          // overwrite in place (K1 refreshes)
}

// ---------------- K3b: W-in-registers MFMA GEMM + blend epilogue --------------
__global__ __launch_bounds__(512) void k3b_gemm(const float* __restrict__ feat,
    const u8* __restrict__ idxb, const float* __restrict__ alphag,
    const float* __restrict__ chatg, const unsigned short* __restrict__ wks,
    const float* __restrict__ fcb, float* __restrict__ out) {
  // featT stride 264 ushorts (528B = 4 banks mod 32) -> min-cycle b128 LDS ops
  __shared__ alignas(16) unsigned short featT[64 * 264];
  const int t = threadIdx.x;
  const int w = t >> 6, ln = t & 63, lo = ln & 15, hi = ln >> 4;

  // W fragments: wave w owns out channels [w*32, w*32+32) -> 2 m-tiles, all 8 k
  bf16x8 wf[2][8];
  #pragma unroll
  for (int ml = 0; ml < 2; ++ml)
    #pragma unroll
    for (int ks = 0; ks < 8; ++ks)
      wf[ml][ks] = *(const bf16x8*)&wks[((size_t)ks * 256 + (w * 2 + ml) * 16 + lo) * 32 + hi * 8];
  f32x4 bias2[2];
  #pragma unroll
  for (int ml = 0; ml < 2; ++ml)
    bias2[ml] = *(const f32x4*)&fcb[w * 32 + ml * 16 + hi * 4];

  for (int rep = 0; rep < 2; ++rep) {
    int tile = blockIdx.x * 2 + rep;               // adjacent tiles: DRAM locality
    int b = tile >> 8;
    int p0 = (tile & 255) << 6;

    { // stage featT: 8 ch-groups x 64 px, transpose f32->bf16
      int pl = t & 63, cph = t >> 6;
      const float* fb = feat + ((size_t)b * 256 + cph * 32) * 16384 + p0 + pl;
      #pragma unroll
      for (int jj = 0; jj < 4; ++jj) {
        union { unsigned short u[8]; uint4 q; } pk;
        #pragma unroll
        for (int e = 0; e < 8; ++e) pk.u[e] = f2b(fb[(size_t)(jj * 8 + e) * 16384]);
        *(uint4*)&featT[pl * 264 + cph * 32 + jj * 8] = pk.q;
      }
    }
    __syncthreads();

    f32x4 acc[2][4];
    f32x4 zz = {0.f, 0.f, 0.f, 0.f};
    #pragma unroll
    for (int ml = 0; ml < 2; ++ml)
      #pragma unroll
      for (int pt = 0; pt < 4; ++pt) acc[ml][pt] = zz;

    #pragma unroll
    for (int ks = 0; ks < 8; ++ks) {
      bf16x8 bfr[4];
      #pragma unroll
      for (int pt = 0; pt < 4; ++pt)
        bfr[pt] = *(const bf16x8*)&featT[(pt * 16 + lo) * 264 + ks * 32 + hi * 8];
      #pragma unroll
      for (int ml = 0; ml < 2; ++ml)
        #pragma unroll
        for (int pt = 0; pt < 4; ++pt)
          acc[ml][pt] = __builtin_amdgcn_mfma_f32_16x16x32_bf16(wf[ml][ks], bfr[pt], acc[ml][pt], 0, 0, 0);
    }

    // epilogue: per-lane blend; alpha/idx/chat from L2
    #pragma unroll
    for (int pt = 0; pt < 4; ++pt) {
      int p = p0 + pt * 16 + lo;
      float a = alphag[(size_t)b * 16384 + p];
      float om = 1.f - a;
      int cid = idxb[b * 16384 + p];
      const float* crow = chatg + ((size_t)b * 80 + cid) * 256;
      #pragma unroll
      for (int ml = 0; ml < 2; ++ml) {
        int o0 = w * 32 + ml * 16 + hi * 4;
        float4 c4 = *(const float4*)&crow[o0];
        size_t ob = ((size_t)b * 256 + o0) * 16384 + p;
        out[ob            ] = fmaxf(fmaf(a, c4.x, om * acc[ml][pt][0]) + bias2[ml][0], 0.f);
        out[ob + 16384    ] = fmaxf(fmaf(a, c4.y, om * acc[ml][pt][1]) + bias2[ml][1], 0.f);
        out[ob + 2 * 16384] = fmaxf(fmaf(a, c4.z, om * acc[ml][pt][2]) + bias2[ml][2], 0.f);
        out[ob + 3 * 16384] = fmaxf(fmaf(a, c4.w, om * acc[ml][pt][3]) + bias2[ml][3], 0.f);
      }
    }
    __syncthreads();   // featT safe to overwrite next rep
  }
}

extern "C" void kernel_launch(void* const* d_in, const int* in_sizes, int n_in,
                              void* d_out, int out_size, void* d_ws, size_t ws_size,
                              hipStream_t stream) {
  (void)in_sizes; (void)n_in; (void)out_size; (void)ws_size;
  const float* feat = (const float*)d_in[0];
  const float* cent = (const float*)d_in[1];
  const float* fcw  = (const float*)d_in[2];
  const float* fcb  = (const float*)d_in[3];
  float* out = (float*)d_out;
  char* ws = (char*)d_ws;
  float* cnT             = (float*)(ws);
  float* wt              = (float*)(ws + 81920);
  unsigned short* wks    = (unsigned short*)(ws + 344064);
  unsigned short* centf  = (unsigned short*)(ws + 475136);
  u8*    idxb            = (u8*)(ws + 1130496);
  float* fsq_alpha       = (float*)(ws + 1392640);
  int*   cntg            = (int*)(ws + 2441216);
  float* csq             = (float*)(ws + 2446336);
  float* chat            = (float*)(ws + 2451456);
  unsigned short* sumxp  = (unsigned short*)(ws + 3762176);

  hipMemsetAsync(cntg, 0, 16 * 80 * sizeof(int), stream);
  k0_cnorm<<<80, 256, 0, stream>>>(cent, cnT);
  k0_wprep<<<256, 256, 0, stream>>>(fcw, wks, wt);
  k1_argmax<<<1024, 256, 0, stream>>>(feat, cnT, idxb, fsq_alpha, cntg);
  k1b_gemm<<<512, 256, 0, stream>>>(feat, idxb, sumxp);
  k2_cent<<<1280, 256, 0, stream>>>(sumxp, cntg, wt, centf, csq, chat);
  k3a_alpha<<<1024, 256, 0, stream>>>(feat, idxb, csq, centf, fsq_alpha);
  k3b_gemm<<<2048, 512, 0, stream>>>(feat, idxb, fsq_alpha, chat, wks, fcb, out);
}

// Round 5
// 465.646 us; speedup vs baseline: 2.0107x; 1.0362x over previous
//
#include <hip/hip_runtime.h>

// Refine: out = relu((1-a)*(W f) + a*chat[idx] + bias)
// a = exp(-(csq - 2*<f,cent[idx]> + fsq)/256), chat = W*cent
// idx = argmax_n <f, cnorm_n>
//
// ws layout (6.38 MB):
//  cnT    [256][80] f32        @ 0
//  wt     [256][256] f32       @ 81920
//  wks    [8][256][32] bf16    @ 344064
//  centf  [16][80][256] bf16   @ 475136
//  idxb   [16*16384] u8        @ 1130496
//  fsq    [16*16384] f32       @ 1392640
//  cnt    [16*80] i32          @ 2441216  (zeroed by k0_cnorm each launch)
//  csq    [16*80] f32          @ 2446336
//  chat   [16][80][256] f32    @ 2451456
//  sumxp  [4][16][80][256] bf16 @ 3762176

typedef __bf16 bf16x8 __attribute__((ext_vector_type(8)));
typedef float  f32x4  __attribute__((ext_vector_type(4)));
typedef unsigned char u8;

__device__ __forceinline__ unsigned short f2b(float f) {
  unsigned u = __float_as_uint(f);
  return (unsigned short)((u + 0x7fffu + ((u >> 16) & 1u)) >> 16);
}
__device__ __forceinline__ float b2f(unsigned short s) {
  return __uint_as_float((unsigned)s << 16);
}

// ---------------- K0a: normalized centroids [c][n] + zero cntg ----------------
__global__ __launch_bounds__(256) void k0_cnorm(const float* __restrict__ cent,
                                                float* __restrict__ cnT,
                                                int* __restrict__ cntg) {
  int n = blockIdx.x, t = threadIdx.x;
  if (t < 16) cntg[n * 16 + t] = 0;               // 80*16 = 1280 ints, no memset kernel
  float v = cent[n * 256 + t];
  float s = v * v;
  #pragma unroll
  for (int o = 32; o > 0; o >>= 1) s += __shfl_down(s, o, 64);
  __shared__ float red[4];
  if ((t & 63) == 0) red[t >> 6] = s;
  __syncthreads();
  float tot = red[0] + red[1] + red[2] + red[3];
  float dn = fmaxf(sqrtf(tot), 1e-12f);
  cnT[t * 80 + n] = v / dn;
}

// ---------------- K0b: W prep: bf16 k-sliced [k][o][32] + W^T f32 -------------
__global__ __launch_bounds__(256) void k0_wprep(const float* __restrict__ fcw,
                                                unsigned short* __restrict__ wks,
                                                float* __restrict__ wt) {
  int o = blockIdx.x, c = threadIdx.x;
  float w = fcw[o * 256 + c];
  wt[c * 256 + o] = w;
  wks[((c >> 5) * 256 + o) * 32 + (c & 31)] = f2b(w);
}

// ---------------- K1: per-pixel argmax over 80 dots (f32) + fsq + counts ------
__global__ __launch_bounds__(256) void k1_argmax(const float* __restrict__ feat,
                                                 const float* __restrict__ cnT,
                                                 u8* __restrict__ idxb,
                                                 float* __restrict__ fsqg,
                                                 int* __restrict__ cntg) {
  __shared__ int lh[80];
  int t = threadIdx.x;
  if (t < 80) lh[t] = 0;
  __syncthreads();
  int b = blockIdx.x >> 6;
  int pi = ((blockIdx.x & 63) << 8) | t;
  const float* fb = feat + (size_t)b * 256 * 16384 + pi;
  float g[80];
  #pragma unroll
  for (int n = 0; n < 80; ++n) g[n] = 0.f;
  float fsq = 0.f;
  #pragma unroll 4
  for (int c = 0; c < 256; ++c) {
    float v = fb[(size_t)c * 16384];
    fsq = fmaf(v, v, fsq);
    const float* cr = cnT + c * 80;
    #pragma unroll
    for (int n = 0; n < 80; ++n) g[n] = fmaf(v, cr[n], g[n]);
  }
  float best = g[0]; int bi = 0;
  #pragma unroll
  for (int n = 1; n < 80; ++n) if (g[n] > best) { best = g[n]; bi = n; }
  idxb[b * 16384 + pi] = (u8)bi;
  fsqg[b * 16384 + pi] = fsq;
  atomicAdd(&lh[bi], 1);
  __syncthreads();
  if (t < 80) atomicAdd(&cntg[b * 80 + t], lh[t]);
}

// ---------------- K1b: sumx = onehot(idx) * feat^T via MFMA (split-K=4) -------
__global__ __launch_bounds__(256) void k1b_gemm(const float* __restrict__ feat,
                                                const u8* __restrict__ idxb,
                                                unsigned short* __restrict__ sumxp) {
  int bid = blockIdx.x;
  int kp = bid & 3, ns = (bid >> 2) & 7, b = bid >> 5;
  int t = threadIdx.x, wv = t >> 6, ln = t & 63, lo = ln & 15, hi = ln >> 4;
  int nt = wv & 1;
  int m0 = (wv >> 1) ? 3 : 0, nm = (wv >> 1) ? 2 : 3;
  int c = ns * 32 + nt * 16 + lo;
  const float* fp = feat + (((size_t)b * 256 + c) * 16384 + kp * 4096 + hi * 8);
  const u8* ip = idxb + b * 16384 + kp * 4096 + hi * 8;
  f32x4 acc[3];
  f32x4 zz = {0.f, 0.f, 0.f, 0.f};
  acc[0] = zz; acc[1] = zz; acc[2] = zz;
  for (int ks = 0; ks < 128; ++ks) {
    float4 v0 = *(const float4*)(fp + ks * 32);
    float4 v1 = *(const float4*)(fp + ks * 32 + 4);
    union { unsigned short u[8]; bf16x8 v; } bb;
    bb.u[0] = f2b(v0.x); bb.u[1] = f2b(v0.y); bb.u[2] = f2b(v0.z); bb.u[3] = f2b(v0.w);
    bb.u[4] = f2b(v1.x); bb.u[5] = f2b(v1.y); bb.u[6] = f2b(v1.z); bb.u[7] = f2b(v1.w);
    uint2 iv = *(const uint2*)(ip + ks * 32);
    int id[8];
    #pragma unroll
    for (int j = 0; j < 4; ++j) { id[j] = (iv.x >> (8 * j)) & 255; id[4 + j] = (iv.y >> (8 * j)) & 255; }
    #pragma unroll
    for (int mi = 0; mi < 3; ++mi) {
      if (mi >= nm) break;
      int row = (m0 + mi) * 16 + lo;
      union { unsigned short u[8]; bf16x8 v; } ma;
      #pragma unroll
      for (int j = 0; j < 8; ++j) ma.u[j] = (id[j] == row) ? (unsigned short)0x3F80 : (unsigned short)0;
      acc[mi] = __builtin_amdgcn_mfma_f32_16x16x32_bf16(ma.v, bb.v, acc[mi], 0, 0, 0);
    }
  }
  #pragma unroll
  for (int mi = 0; mi < 3; ++mi) {
    if (mi >= nm) break;
    #pragma unroll
    for (int r = 0; r < 4; ++r) {
      int cls = (m0 + mi) * 16 + hi * 4 + r;
      sumxp[(((size_t)kp * 16 + b) * 80 + cls) * 256 + ns * 32 + nt * 16 + lo] = f2b(acc[mi][r]);
    }
  }
}

// ---------------- K2: cent = sum/max(cnt,1); csq; centf bf16; chat = W*cent ---
__global__ __launch_bounds__(256) void k2_cent(const unsigned short* __restrict__ sumxp,
                                               const int* __restrict__ cntg,
                                               const float* __restrict__ wt,
                                               unsigned short* __restrict__ centf,
                                               float* __restrict__ csqg,
                                               float* __restrict__ chatg) {
  int bn = blockIdx.x; int t = threadIdx.x;
  float dn = fmaxf((float)cntg[bn], 1.0f);
  float s = 0.f;
  #pragma unroll
  for (int kp = 0; kp < 4; ++kp)
    s += b2f(sumxp[((size_t)kp * 1280 + bn) * 256 + t]);   // [kp][b][n][c]
  float cv = s / dn;
  __shared__ float cl[256];
  __shared__ float red[4];
  cl[t] = cv;
  centf[(size_t)bn * 256 + t] = f2b(cv);
  float q = cv * cv;
  #pragma unroll
  for (int o = 32; o > 0; o >>= 1) q += __shfl_down(q, o, 64);
  if ((t & 63) == 0) red[t >> 6] = q;
  __syncthreads();
  if (t == 0) csqg[bn] = red[0] + red[1] + red[2] + red[3];
  float acc = 0.f;
  #pragma unroll 4
  for (int c = 0; c < 256; ++c) acc = fmaf(wt[c * 256 + t], cl[c], acc);
  chatg[(size_t)bn * 256 + t] = acc;
}

// ---------------- K3b: W-in-registers MFMA GEMM + fused alpha + epilogue ------
__global__ __launch_bounds__(512) void k3b_gemm(const float* __restrict__ feat,
    const u8* __restrict__ idxb, const float* __restrict__ fsqg,
    const float* __restrict__ csqg, const unsigned short* __restrict__ centf,
    const float* __restrict__ chatg, const unsigned short* __restrict__ wks,
    const float* __restrict__ fcb, float* __restrict__ out) {
  // featT stride 264 ushorts (528B = 4 banks mod 32) -> min-cycle b128 LDS ops
  __shared__ alignas(16) unsigned short featT[64 * 264];
  __shared__ float alphal[64];
  const int t = threadIdx.x;
  const int w = t >> 6, ln = t & 63, lo = ln & 15, hi = ln >> 4;

  // W fragments: wave w owns out channels [w*32, w*32+32) -> 2 m-tiles, all 8 k
  bf16x8 wf[2][8];
  #pragma unroll
  for (int ml = 0; ml < 2; ++ml)
    #pragma unroll
    for (int ks = 0; ks < 8; ++ks)
      wf[ml][ks] = *(const bf16x8*)&wks[((size_t)ks * 256 + (w * 2 + ml) * 16 + lo) * 32 + hi * 8];
  f32x4 bias2[2];
  #pragma unroll
  for (int ml = 0; ml < 2; ++ml)
    bias2[ml] = *(const f32x4*)&fcb[w * 32 + ml * 16 + hi * 4];

  for (int rep = 0; rep < 2; ++rep) {
    int tile = blockIdx.x * 2 + rep;               // adjacent tiles: DRAM locality
    int b = tile >> 8;
    int p0 = (tile & 255) << 6;

    { // stage featT: 8 ch-groups x 64 px, transpose f32->bf16
      int pl = t & 63, cph = t >> 6;
      const float* fb = feat + ((size_t)b * 256 + cph * 32) * 16384 + p0 + pl;
      #pragma unroll
      for (int jj = 0; jj < 4; ++jj) {
        union { unsigned short u[8]; uint4 q; } pk;
        #pragma unroll
        for (int e = 0; e < 8; ++e) pk.u[e] = f2b(fb[(size_t)(jj * 8 + e) * 16384]);
        *(uint4*)&featT[pl * 264 + cph * 32 + jj * 8] = pk.q;
      }
    }
    __syncthreads();

    { // fused alpha: 8 threads per pixel, 32 channels each, shfl-reduce
      int p = t >> 3, sub = t & 7;
      int cid = idxb[b * 16384 + p0 + p];
      const unsigned short* cw = centf + ((size_t)b * 80 + cid) * 256 + sub * 32;
      const unsigned short* fr = &featT[p * 264 + sub * 32];
      float sel = 0.f;
      #pragma unroll
      for (int j = 0; j < 4; ++j) {
        uint4 cc = *(const uint4*)&cw[j * 8];
        uint4 ff = *(const uint4*)&fr[j * 8];
        sel = fmaf(b2f((unsigned short)(ff.x & 0xffff)), b2f((unsigned short)(cc.x & 0xffff)), sel);
        sel = fmaf(b2f((unsigned short)(ff.x >> 16)),    b2f((unsigned short)(cc.x >> 16)),    sel);
        sel = fmaf(b2f((unsigned short)(ff.y & 0xffff)), b2f((unsigned short)(cc.y & 0xffff)), sel);
        sel = fmaf(b2f((unsigned short)(ff.y >> 16)),    b2f((unsigned short)(cc.y >> 16)),    sel);
        sel = fmaf(b2f((unsigned short)(ff.z & 0xffff)), b2f((unsigned short)(cc.z & 0xffff)), sel);
        sel = fmaf(b2f((unsigned short)(ff.z >> 16)),    b2f((unsigned short)(cc.z >> 16)),    sel);
        sel = fmaf(b2f((unsigned short)(ff.w & 0xffff)), b2f((unsigned short)(cc.w & 0xffff)), sel);
        sel = fmaf(b2f((unsigned short)(ff.w >> 16)),    b2f((unsigned short)(cc.w >> 16)),    sel);
      }
      sel += __shfl_xor(sel, 1, 64);
      sel += __shfl_xor(sel, 2, 64);
      sel += __shfl_xor(sel, 4, 64);
      if (sub == 0) {
        float fsq = fsqg[b * 16384 + p0 + p];
        float msq = (csqg[b * 80 + cid] - 2.f * sel + fsq) * (1.f / 256.f);
        alphal[p] = expf(-msq);
      }
    }

    f32x4 acc[2][4];
    f32x4 zz = {0.f, 0.f, 0.f, 0.f};
    #pragma unroll
    for (int ml = 0; ml < 2; ++ml)
      #pragma unroll
      for (int pt = 0; pt < 4; ++pt) acc[ml][pt] = zz;

    #pragma unroll
    for (int ks = 0; ks < 8; ++ks) {
      bf16x8 bfr[4];
      #pragma unroll
      for (int pt = 0; pt < 4; ++pt)
        bfr[pt] = *(const bf16x8*)&featT[(pt * 16 + lo) * 264 + ks * 32 + hi * 8];
      #pragma unroll
      for (int ml = 0; ml < 2; ++ml)
        #pragma unroll
        for (int pt = 0; pt < 4; ++pt)
          acc[ml][pt] = __builtin_amdgcn_mfma_f32_16x16x32_bf16(wf[ml][ks], bfr[pt], acc[ml][pt], 0, 0, 0);
    }
    __syncthreads();   // alphal visible to all; featT reads done

    // epilogue: per-lane blend; idx/chat from L2, alpha from LDS
    #pragma unroll
    for (int pt = 0; pt < 4; ++pt) {
      int pl = pt * 16 + lo;
      int p = p0 + pl;
      float a = alphal[pl];
      float om = 1.f - a;
      int cid = idxb[b * 16384 + p];
      const float* crow = chatg + ((size_t)b * 80 + cid) * 256;
      #pragma unroll
      for (int ml = 0; ml < 2; ++ml) {
        int o0 = w * 32 + ml * 16 + hi * 4;
        float4 c4 = *(const float4*)&crow[o0];
        size_t ob = ((size_t)b * 256 + o0) * 16384 + p;
        out[ob            ] = fmaxf(fmaf(a, c4.x, om * acc[ml][pt][0]) + bias2[ml][0], 0.f);
        out[ob + 16384    ] = fmaxf(fmaf(a, c4.y, om * acc[ml][pt][1]) + bias2[ml][1], 0.f);
        out[ob + 2 * 16384] = fmaxf(fmaf(a, c4.z, om * acc[ml][pt][2]) + bias2[ml][2], 0.f);
        out[ob + 3 * 16384] = fmaxf(fmaf(a, c4.w, om * acc[ml][pt][3]) + bias2[ml][3], 0.f);
      }
    }
    __syncthreads();   // featT/alphal safe to overwrite next rep
  }
}

extern "C" void kernel_launch(void* const* d_in, const int* in_sizes, int n_in,
                              void* d_out, int out_size, void* d_ws, size_t ws_size,
                              hipStream_t stream) {
  (void)in_sizes; (void)n_in; (void)out_size; (void)ws_size;
  const float* feat = (const float*)d_in[0];
  const float* cent = (const float*)d_in[1];
  const float* fcw  = (const float*)d_in[2];
  const float* fcb  = (const float*)d_in[3];
  float* out = (float*)d_out;
  char* ws = (char*)d_ws;
  float* cnT             = (float*)(ws);
  float* wt              = (float*)(ws + 81920);
  unsigned short* wks    = (unsigned short*)(ws + 344064);
  unsigned short* centf  = (unsigned short*)(ws + 475136);
  u8*    idxb            = (u8*)(ws + 1130496);
  float* fsq             = (float*)(ws + 1392640);
  int*   cntg            = (int*)(ws + 2441216);
  float* csq             = (float*)(ws + 2446336);
  float* chat            = (float*)(ws + 2451456);
  unsigned short* sumxp  = (unsigned short*)(ws + 3762176);

  k0_cnorm<<<80, 256, 0, stream>>>(cent, cnT, cntg);
  k0_wprep<<<256, 256, 0, stream>>>(fcw, wks, wt);
  k1_argmax<<<1024, 256, 0, stream>>>(feat, cnT, idxb, fsq, cntg);
  k1b_gemm<<<512, 256, 0, stream>>>(feat, idxb, sumxp);
  k2_cent<<<1280, 256, 0, stream>>>(sumxp, cntg, wt, centf, csq, chat);
  k3b_gemm<<<2048, 512, 0, stream>>>(feat, idxb, fsq, csq, centf, chat, wks, fcb, out);
}